// Round 7
// baseline (1396.169 us; speedup 1.0000x reference)
//
#include <hip/hip_runtime.h>
#include <cmath>

#define NN 50000
#define EE 800000
#define H1C 128        // heads*hid layer1
#define OUTC 64
#define EDIM 32
#define NBLK 196       // ceil(NN/256)

// ---------------- CSR build ----------------

__global__ void k_hist(const int* __restrict__ ei, int* deg) {
    int e = blockIdx.x * 256 + threadIdx.x;
    if (e < EE) atomicAdd(&deg[ei[EE + e]], 1);
}

__global__ void k_scan_block(const int* __restrict__ deg, int* offs, int* bsum) {
    __shared__ int s[256];
    int t = threadIdx.x;
    int gid = blockIdx.x * 256 + t;
    int v = (gid < NN) ? deg[gid] : 0;
    s[t] = v;
    __syncthreads();
    for (int off = 1; off < 256; off <<= 1) {
        int add = (t >= off) ? s[t - off] : 0;
        __syncthreads();
        s[t] += add;
        __syncthreads();
    }
    if (gid < NN) offs[gid] = s[t] - v;          // exclusive within block
    if (t == 255) bsum[blockIdx.x] = s[255];
}

__global__ void k_scan_top(const int* __restrict__ bsum, int* bexcl) {
    __shared__ int s[256];
    int t = threadIdx.x;
    int v = (t < NBLK) ? bsum[t] : 0;
    s[t] = v;
    __syncthreads();
    for (int off = 1; off < 256; off <<= 1) {
        int add = (t >= off) ? s[t - off] : 0;
        __syncthreads();
        s[t] += add;
        __syncthreads();
    }
    bexcl[t] = s[t] - v;
}

__global__ void k_scan_add(int* offs, const int* __restrict__ bexcl) {
    int gid = blockIdx.x * 256 + threadIdx.x;
    if (gid < NN) offs[gid] += bexcl[blockIdx.x];
    if (gid == 0) offs[NN] = EE;
}

__global__ void k_scatter(const int* __restrict__ ei, const int* __restrict__ offs,
                          int* deg, int2* esort) {
    int e = blockIdx.x * 256 + threadIdx.x;
    if (e >= EE) return;
    int dst = ei[EE + e];
    int idx = atomicSub(&deg[dst], 1) - 1;
    esort[offs[dst] + idx] = make_int2(ei[e], e);
}

// ---------------- fused pair of linears: oa = x@Wa+ba, ob = x@Wb+bb ----------------

template <int MO>
__global__ void k_lin_pair(const float* __restrict__ x,
                           const float* __restrict__ Wa, const float* __restrict__ ba,
                           const float* __restrict__ Wb, const float* __restrict__ bb,
                           float* __restrict__ oa, float* __restrict__ ob) {
    __shared__ float xsT[128][36];   // transposed tile, padded
    int n0 = blockIdx.x * 32;
    int nthr = 2 * MO;
    for (int idx = threadIdx.x; idx < 32 * 128; idx += nthr) {
        int n = idx >> 7, k = idx & 127;
        xsT[k][n] = (n0 + n < NN) ? x[(size_t)(n0 + n) * 128 + k] : 0.f;
    }
    __syncthreads();
    int t = threadIdx.x;
    const float* W  = (t < MO) ? Wa : Wb;
    const float* bp = (t < MO) ? ba : bb;
    float* op       = (t < MO) ? oa : ob;
    int m = (t < MO) ? t : t - MO;
    float bv = bp[m];
    float acc[32];
#pragma unroll
    for (int n = 0; n < 32; ++n) acc[n] = bv;
#pragma unroll 2
    for (int k = 0; k < 128; ++k) {
        float w = W[k * MO + m];
        const float4* row = reinterpret_cast<const float4*>(&xsT[k][0]);
#pragma unroll
        for (int c = 0; c < 8; ++c) {
            float4 v = row[c];
            acc[4 * c + 0] = fmaf(v.x, w, acc[4 * c + 0]);
            acc[4 * c + 1] = fmaf(v.y, w, acc[4 * c + 1]);
            acc[4 * c + 2] = fmaf(v.z, w, acc[4 * c + 2]);
            acc[4 * c + 3] = fmaf(v.w, w, acc[4 * c + 3]);
        }
    }
#pragma unroll
    for (int n = 0; n < 32; ++n)
        if (n0 + n < NN) op[(size_t)(n0 + n) * MO + m] = acc[n];
}

// ---------------- fused edge phase, layer 1 (2 heads x 64) ----------------

__device__ __forceinline__ void edge_upd1(float xl0, float xl1, float av,
                                          float xr0, float xr1, float a0, float a1,
                                          const float* sWe, int lane,
                                          float& mr0, float& mr1, float& s0, float& s1,
                                          float& acc0, float& acc1) {
    float m0 = xl0 + xr0, m1 = xl1 + xr1;
#pragma unroll
    for (int d = 0; d < EDIM; ++d) {
        float a = __shfl(av, d);
        m0 = fmaf(a, sWe[d * H1C + lane], m0);
        m1 = fmaf(a, sWe[d * H1C + 64 + lane], m1);
    }
    m0 = m0 > 0.f ? m0 : 0.2f * m0;
    m1 = m1 > 0.f ? m1 : 0.2f * m1;
    float p0 = m0 * a0, p1 = m1 * a1;
#pragma unroll
    for (int off = 32; off; off >>= 1) { p0 += __shfl_xor(p0, off); p1 += __shfl_xor(p1, off); }
    float nm = fmaxf(mr0, p0);
    float sc = __expf(mr0 - nm), e = __expf(p0 - nm);
    s0 = s0 * sc + e; acc0 = fmaf(acc0, sc, e * xl0); mr0 = nm;
    nm = fmaxf(mr1, p1);
    sc = __expf(mr1 - nm); e = __expf(p1 - nm);
    s1 = s1 * sc + e; acc1 = fmaf(acc1, sc, e * xl1); mr1 = nm;
}

__global__ void __launch_bounds__(256) k_l1(
    const int2* __restrict__ esort, const int* __restrict__ offs,
    const float* __restrict__ ea, const float* __restrict__ We,
    const float* __restrict__ att, const float* __restrict__ xl,
    const float* __restrict__ xr, const float* __restrict__ bias,
    float* __restrict__ hb) {
    __shared__ float sWe[EDIM * H1C];   // 16 KB
    for (int i = threadIdx.x; i < EDIM * H1C; i += 256) sWe[i] = We[i];
    __syncthreads();
    int lane = threadIdx.x & 63;
    int dst = (blockIdx.x << 2) + (threadIdx.x >> 6);
    if (dst >= NN) return;
    int beg = offs[dst], end = offs[dst + 1];
    float a0 = att[lane], a1 = att[64 + lane];
    size_t db = (size_t)dst * H1C;
    float xr0 = xr[db + lane], xr1 = xr[db + 64 + lane];
    float mr0 = -INFINITY, mr1 = -INFINITY;
    float s0 = 0.f, s1 = 0.f, acc0 = 0.f, acc1 = 0.f, easum = 0.f;

    // chunked: lane-cooperative load of up to 64 CSR entries → addresses in regs
    for (int base = beg; base < end; base += 64) {
        int nchunk = min(64, end - base);
        int2 edv = esort[base + min(lane, nchunk - 1)];
        int esrc = edv.x, eidx = edv.y;

        // depth-2 software pipeline over this chunk (static buffer indexing)
        float Axl0 = 0.f, Axl1 = 0.f, Aav = 0.f;
        float Bxl0 = 0.f, Bxl1 = 0.f, Bav = 0.f;
        {
            int s = __shfl(esrc, 0), y = __shfl(eidx, 0);
            size_t sb = (size_t)s * H1C;
            Axl0 = xl[sb + lane]; Axl1 = xl[sb + 64 + lane];
            Aav = ea[(size_t)y * EDIM + (lane & 31)];
        }
        if (nchunk > 1) {
            int s = __shfl(esrc, 1), y = __shfl(eidx, 1);
            size_t sb = (size_t)s * H1C;
            Bxl0 = xl[sb + lane]; Bxl1 = xl[sb + 64 + lane];
            Bav = ea[(size_t)y * EDIM + (lane & 31)];
        }
        int j = 0;
        while (j + 2 <= nchunk) {
            easum += Aav;
            edge_upd1(Axl0, Axl1, Aav, xr0, xr1, a0, a1, sWe, lane, mr0, mr1, s0, s1, acc0, acc1);
            if (j + 2 < nchunk) {
                int s = __shfl(esrc, j + 2), y = __shfl(eidx, j + 2);
                size_t sb = (size_t)s * H1C;
                Axl0 = xl[sb + lane]; Axl1 = xl[sb + 64 + lane];
                Aav = ea[(size_t)y * EDIM + (lane & 31)];
            }
            easum += Bav;
            edge_upd1(Bxl0, Bxl1, Bav, xr0, xr1, a0, a1, sWe, lane, mr0, mr1, s0, s1, acc0, acc1);
            if (j + 3 < nchunk) {
                int s = __shfl(esrc, j + 3), y = __shfl(eidx, j + 3);
                size_t sb = (size_t)s * H1C;
                Bxl0 = xl[sb + lane]; Bxl1 = xl[sb + 64 + lane];
                Bav = ea[(size_t)y * EDIM + (lane & 31)];
            }
            j += 2;
        }
        if (j < nchunk) {
            easum += Aav;
            edge_upd1(Axl0, Axl1, Aav, xr0, xr1, a0, a1, sWe, lane, mr0, mr1, s0, s1, acc0, acc1);
        }
    }

    // self loop: attr = mean of incoming edge attrs (0 if no edges)
    int deg = end - beg;
    float lav = easum * ((deg > 0) ? (1.f / (float)deg) : 1.f);
    float sxl0 = xl[db + lane], sxl1 = xl[db + 64 + lane];
    edge_upd1(sxl0, sxl1, lav, xr0, xr1, a0, a1, sWe, lane, mr0, mr1, s0, s1, acc0, acc1);

    float h0 = acc0 / (s0 + 1e-16f) + bias[lane];
    float h1 = acc1 / (s1 + 1e-16f) + bias[64 + lane];
    hb[db + lane]      = h0 > 0.f ? h0 : expm1f(h0);
    hb[db + 64 + lane] = h1 > 0.f ? h1 : expm1f(h1);
}

// ---------------- fused edge phase, layer 2 (1 head x 64) ----------------

__device__ __forceinline__ void edge_upd2(float xlv, float av, float xrv, float a,
                                          const float* sWe, int lane,
                                          float& mr, float& s, float& acc) {
    float m = xlv + xrv;
#pragma unroll
    for (int d = 0; d < EDIM; ++d)
        m = fmaf(__shfl(av, d), sWe[d * OUTC + lane], m);
    m = m > 0.f ? m : 0.2f * m;
    float p = m * a;
#pragma unroll
    for (int off = 32; off; off >>= 1) p += __shfl_xor(p, off);
    float nm = fmaxf(mr, p);
    float sc = __expf(mr - nm), e = __expf(p - nm);
    s = s * sc + e; acc = fmaf(acc, sc, e * xlv); mr = nm;
}

__global__ void __launch_bounds__(256) k_l2(
    const int2* __restrict__ esort, const int* __restrict__ offs,
    const float* __restrict__ ea, const float* __restrict__ We,
    const float* __restrict__ att, const float* __restrict__ xl,
    const float* __restrict__ xr, const float* __restrict__ bias,
    float* __restrict__ out) {
    __shared__ float sWe[EDIM * OUTC];  // 8 KB
    for (int i = threadIdx.x; i < EDIM * OUTC; i += 256) sWe[i] = We[i];
    __syncthreads();
    int lane = threadIdx.x & 63;
    int dst = (blockIdx.x << 2) + (threadIdx.x >> 6);
    if (dst >= NN) return;
    int beg = offs[dst], end = offs[dst + 1];
    float a = att[lane];
    size_t db = (size_t)dst * OUTC;
    float xrv = xr[db + lane];
    float mr = -INFINITY, s = 0.f, acc = 0.f, easum = 0.f;

    for (int base = beg; base < end; base += 64) {
        int nchunk = min(64, end - base);
        int2 edv = esort[base + min(lane, nchunk - 1)];
        int esrc = edv.x, eidx = edv.y;

        float Axl = 0.f, Aav = 0.f, Bxl = 0.f, Bav = 0.f;
        {
            int sj = __shfl(esrc, 0), y = __shfl(eidx, 0);
            Axl = xl[(size_t)sj * OUTC + lane];
            Aav = ea[(size_t)y * EDIM + (lane & 31)];
        }
        if (nchunk > 1) {
            int sj = __shfl(esrc, 1), y = __shfl(eidx, 1);
            Bxl = xl[(size_t)sj * OUTC + lane];
            Bav = ea[(size_t)y * EDIM + (lane & 31)];
        }
        int j = 0;
        while (j + 2 <= nchunk) {
            easum += Aav;
            edge_upd2(Axl, Aav, xrv, a, sWe, lane, mr, s, acc);
            if (j + 2 < nchunk) {
                int sj = __shfl(esrc, j + 2), y = __shfl(eidx, j + 2);
                Axl = xl[(size_t)sj * OUTC + lane];
                Aav = ea[(size_t)y * EDIM + (lane & 31)];
            }
            easum += Bav;
            edge_upd2(Bxl, Bav, xrv, a, sWe, lane, mr, s, acc);
            if (j + 3 < nchunk) {
                int sj = __shfl(esrc, j + 3), y = __shfl(eidx, j + 3);
                Bxl = xl[(size_t)sj * OUTC + lane];
                Bav = ea[(size_t)y * EDIM + (lane & 31)];
            }
            j += 2;
        }
        if (j < nchunk) {
            easum += Aav;
            edge_upd2(Axl, Aav, xrv, a, sWe, lane, mr, s, acc);
        }
    }

    int deg = end - beg;
    float lav = easum * ((deg > 0) ? (1.f / (float)deg) : 1.f);
    float sxl = xl[db + lane];
    edge_upd2(sxl, lav, xrv, a, sWe, lane, mr, s, acc);

    out[db + lane] = acc / (s + 1e-16f) + bias[lane];
}

// ---------------- launch ----------------

extern "C" void kernel_launch(void* const* d_in, const int* in_sizes, int n_in,
                              void* d_out, int out_size, void* d_ws, size_t ws_size,
                              hipStream_t stream) {
    const float* x    = (const float*)d_in[0];
    const int*   ei   = (const int*)d_in[1];
    const float* ea   = (const float*)d_in[2];
    const float* Wl1  = (const float*)d_in[3];
    const float* bl1  = (const float*)d_in[4];
    const float* Wr1  = (const float*)d_in[5];
    const float* br1  = (const float*)d_in[6];
    const float* We1  = (const float*)d_in[7];
    const float* att1 = (const float*)d_in[8];
    const float* bias1= (const float*)d_in[9];
    const float* Wl2  = (const float*)d_in[10];
    const float* bl2  = (const float*)d_in[11];
    const float* Wr2  = (const float*)d_in[12];
    const float* br2  = (const float*)d_in[13];
    const float* We2  = (const float*)d_in[14];
    const float* att2 = (const float*)d_in[15];
    const float* bias2= (const float*)d_in[16];
    float* out = (float*)d_out;

    char* w = (char*)d_ws;
    int2* esort = (int2*)w;                 w += (size_t)EE * 8;        // 6.4 MB
    int*  offs  = (int*)w;                  w += (size_t)(NN + 4) * 4;
    int*  bsum  = (int*)w;                  w += 256 * 4;
    int*  bexcl = (int*)w;                  w += 256 * 4;
    int*  deg   = (int*)w;                  w += (size_t)NN * 4;
    float* xl1  = (float*)w;                w += (size_t)NN * H1C * 4;
    float* xr1  = (float*)w;                w += (size_t)NN * H1C * 4;
    float* hb   = (float*)w;                w += (size_t)NN * H1C * 4;
    float* xl2  = (float*)w;                w += (size_t)NN * OUTC * 4;
    float* xr2  = (float*)w;                w += (size_t)NN * OUTC * 4;

    hipMemsetAsync(deg, 0, (size_t)NN * 4, stream);

    // CSR build (edges sorted by dst)
    k_hist<<<(EE + 255) / 256, 256, 0, stream>>>(ei, deg);
    k_scan_block<<<NBLK, 256, 0, stream>>>(deg, offs, bsum);
    k_scan_top<<<1, 256, 0, stream>>>(bsum, bexcl);
    k_scan_add<<<NBLK, 256, 0, stream>>>(offs, bexcl);
    k_scatter<<<(EE + 255) / 256, 256, 0, stream>>>(ei, offs, deg, esort);

    // layer 1
    k_lin_pair<128><<<(NN + 31) / 32, 256, 0, stream>>>(x, Wl1, bl1, Wr1, br1, xl1, xr1);
    k_l1<<<(NN + 3) / 4, 256, 0, stream>>>(esort, offs, ea, We1, att1, xl1, xr1, bias1, hb);

    // layer 2
    k_lin_pair<64><<<(NN + 31) / 32, 128, 0, stream>>>(hb, Wl2, bl2, Wr2, br2, xl2, xr2);
    k_l2<<<(NN + 3) / 4, 256, 0, stream>>>(esort, offs, ea, We2, att2, xl2, xr2, bias2, out);
}

// Round 8
// 1299.659 us; speedup vs baseline: 1.0743x; 1.0743x over previous
//
#include <hip/hip_runtime.h>
#include <cmath>

#define NN 50000
#define EE 800000
#define H1C 128        // heads*hid layer1
#define OUTC 64
#define EDIM 32
#define NBLK 196       // ceil(NN/256)

// ---------------- CSR build ----------------

__global__ void k_hist(const int* __restrict__ ei, int* deg) {
    int e = blockIdx.x * 256 + threadIdx.x;
    if (e < EE) atomicAdd(&deg[ei[EE + e]], 1);
}

__global__ void k_scan_block(const int* __restrict__ deg, int* offs, int* bsum) {
    __shared__ int s[256];
    int t = threadIdx.x;
    int gid = blockIdx.x * 256 + t;
    int v = (gid < NN) ? deg[gid] : 0;
    s[t] = v;
    __syncthreads();
    for (int off = 1; off < 256; off <<= 1) {
        int add = (t >= off) ? s[t - off] : 0;
        __syncthreads();
        s[t] += add;
        __syncthreads();
    }
    if (gid < NN) offs[gid] = s[t] - v;          // exclusive within block
    if (t == 255) bsum[blockIdx.x] = s[255];
}

__global__ void k_scan_top(const int* __restrict__ bsum, int* bexcl) {
    __shared__ int s[256];
    int t = threadIdx.x;
    int v = (t < NBLK) ? bsum[t] : 0;
    s[t] = v;
    __syncthreads();
    for (int off = 1; off < 256; off <<= 1) {
        int add = (t >= off) ? s[t - off] : 0;
        __syncthreads();
        s[t] += add;
        __syncthreads();
    }
    bexcl[t] = s[t] - v;
}

__global__ void k_scan_add(int* offs, const int* __restrict__ bexcl) {
    int gid = blockIdx.x * 256 + threadIdx.x;
    if (gid < NN) offs[gid] += bexcl[blockIdx.x];
    if (gid == 0) offs[NN] = EE;
}

__global__ void k_scatter(const int* __restrict__ ei, const int* __restrict__ offs,
                          int* deg, int2* esort) {
    int e = blockIdx.x * 256 + threadIdx.x;
    if (e >= EE) return;
    int dst = ei[EE + e];
    int idx = atomicSub(&deg[dst], 1) - 1;
    esort[offs[dst] + idx] = make_int2(ei[e], e);
}

// ---------------- fused pair of linears: oa = x@Wa+ba, ob = x@Wb+bb ----------------

template <int MO>
__global__ void k_lin_pair(const float* __restrict__ x,
                           const float* __restrict__ Wa, const float* __restrict__ ba,
                           const float* __restrict__ Wb, const float* __restrict__ bb,
                           float* __restrict__ oa, float* __restrict__ ob) {
    __shared__ float xsT[128][36];   // transposed tile, padded
    int n0 = blockIdx.x * 32;
    int nthr = 2 * MO;
    for (int idx = threadIdx.x; idx < 32 * 128; idx += nthr) {
        int n = idx >> 7, k = idx & 127;
        xsT[k][n] = (n0 + n < NN) ? x[(size_t)(n0 + n) * 128 + k] : 0.f;
    }
    __syncthreads();
    int t = threadIdx.x;
    const float* W  = (t < MO) ? Wa : Wb;
    const float* bp = (t < MO) ? ba : bb;
    float* op       = (t < MO) ? oa : ob;
    int m = (t < MO) ? t : t - MO;
    float bv = bp[m];
    float acc[32];
#pragma unroll
    for (int n = 0; n < 32; ++n) acc[n] = bv;
#pragma unroll 2
    for (int k = 0; k < 128; ++k) {
        float w = W[k * MO + m];
        const float4* row = reinterpret_cast<const float4*>(&xsT[k][0]);
#pragma unroll
        for (int c = 0; c < 8; ++c) {
            float4 v = row[c];
            acc[4 * c + 0] = fmaf(v.x, w, acc[4 * c + 0]);
            acc[4 * c + 1] = fmaf(v.y, w, acc[4 * c + 1]);
            acc[4 * c + 2] = fmaf(v.z, w, acc[4 * c + 2]);
            acc[4 * c + 3] = fmaf(v.w, w, acc[4 * c + 3]);
        }
    }
#pragma unroll
    for (int n = 0; n < 32; ++n)
        if (n0 + n < NN) op[(size_t)(n0 + n) * MO + m] = acc[n];
}

// ---------------- fused edge phase, layer 1 (2 heads x 64) ----------------

__device__ __forceinline__ void edge_upd1(float xl0, float xl1, float av,
                                          float xr0, float xr1, float a0, float a1,
                                          const float* sWe, int lane,
                                          float& mr0, float& mr1, float& s0, float& s1,
                                          float& acc0, float& acc1) {
    // split dot chains: 2 partial sums per head (halves VALU critical path)
    float t0 = 0.f, t1 = 0.f, u0 = 0.f, u1 = 0.f;
#pragma unroll
    for (int d = 0; d < 16; ++d) {
        float a = __shfl(av, d);
        t0 = fmaf(a, sWe[d * H1C + lane], t0);
        t1 = fmaf(a, sWe[d * H1C + 64 + lane], t1);
    }
#pragma unroll
    for (int d = 16; d < 32; ++d) {
        float a = __shfl(av, d);
        u0 = fmaf(a, sWe[d * H1C + lane], u0);
        u1 = fmaf(a, sWe[d * H1C + 64 + lane], u1);
    }
    float m0 = (xl0 + xr0) + (t0 + u0);
    float m1 = (xl1 + xr1) + (t1 + u1);
    m0 = m0 > 0.f ? m0 : 0.2f * m0;
    m1 = m1 > 0.f ? m1 : 0.2f * m1;
    float p0 = m0 * a0, p1 = m1 * a1;
#pragma unroll
    for (int off = 32; off; off >>= 1) { p0 += __shfl_xor(p0, off); p1 += __shfl_xor(p1, off); }
    float nm = fmaxf(mr0, p0);
    float sc = __expf(mr0 - nm), e = __expf(p0 - nm);
    s0 = s0 * sc + e; acc0 = fmaf(acc0, sc, e * xl0); mr0 = nm;
    nm = fmaxf(mr1, p1);
    sc = __expf(mr1 - nm); e = __expf(p1 - nm);
    s1 = s1 * sc + e; acc1 = fmaf(acc1, sc, e * xl1); mr1 = nm;
}

__global__ void __launch_bounds__(256) k_l1(
    const int2* __restrict__ esort, const int* __restrict__ offs,
    const float* __restrict__ ea, const float* __restrict__ We,
    const float* __restrict__ att, const float* __restrict__ xl,
    const float* __restrict__ xr, const float* __restrict__ bias,
    float* __restrict__ hb) {
    __shared__ float sWe[EDIM * H1C];   // 16 KB
    for (int i = threadIdx.x; i < EDIM * H1C; i += 256) sWe[i] = We[i];
    __syncthreads();
    int lane = threadIdx.x & 63;
    int dst = (blockIdx.x << 2) + (threadIdx.x >> 6);
    if (dst >= NN) return;
    int beg = offs[dst], end = offs[dst + 1];
    int n = end - beg;
    float a0 = att[lane], a1 = att[64 + lane];
    size_t db = (size_t)dst * H1C;
    float xr0 = xr[db + lane], xr1 = xr[db + 64 + lane];
    float mr0 = -INFINITY, mr1 = -INFINITY;
    float s0 = 0.f, s1 = 0.f, acc0 = 0.f, acc1 = 0.f, easum = 0.f;

    if (n > 0) {
        const int2* ep = esort + beg;
        int lastc = n - 1;
        // index stream prefetched 4-5 ahead; value buffers (A,B) 2 ahead; all clamped, branch-free
        int2 edA = ep[0];
        int2 edB = ep[min(1, lastc)];
        int2 edC = ep[min(2, lastc)];
        int2 edD = ep[min(3, lastc)];
        size_t sb = (size_t)edA.x * H1C;
        float Axl0 = xl[sb + lane], Axl1 = xl[sb + 64 + lane];
        float Aav  = ea[(size_t)edA.y * EDIM + (lane & 31)];
        sb = (size_t)edB.x * H1C;
        float Bxl0 = xl[sb + lane], Bxl1 = xl[sb + 64 + lane];
        float Bav  = ea[(size_t)edB.y * EDIM + (lane & 31)];
        int j = 0;
        while (j + 2 <= n) {
            size_t sbC = (size_t)edC.x * H1C;
            float Cxl0 = xl[sbC + lane], Cxl1 = xl[sbC + 64 + lane];
            float Cav  = ea[(size_t)edC.y * EDIM + (lane & 31)];
            int2 edE = ep[min(j + 4, lastc)];
            easum += Aav;
            edge_upd1(Axl0, Axl1, Aav, xr0, xr1, a0, a1, sWe, lane, mr0, mr1, s0, s1, acc0, acc1);
            size_t sbD = (size_t)edD.x * H1C;
            float Dxl0 = xl[sbD + lane], Dxl1 = xl[sbD + 64 + lane];
            float Dav  = ea[(size_t)edD.y * EDIM + (lane & 31)];
            int2 edF = ep[min(j + 5, lastc)];
            easum += Bav;
            edge_upd1(Bxl0, Bxl1, Bav, xr0, xr1, a0, a1, sWe, lane, mr0, mr1, s0, s1, acc0, acc1);
            Axl0 = Cxl0; Axl1 = Cxl1; Aav = Cav;
            Bxl0 = Dxl0; Bxl1 = Dxl1; Bav = Dav;
            edC = edE; edD = edF;
            j += 2;
        }
        if (j < n) {
            easum += Aav;
            edge_upd1(Axl0, Axl1, Aav, xr0, xr1, a0, a1, sWe, lane, mr0, mr1, s0, s1, acc0, acc1);
        }
    }

    // self loop: attr = mean of incoming edge attrs (0 if no edges)
    float lav = easum * ((n > 0) ? (1.f / (float)n) : 1.f);
    float sxl0 = xl[db + lane], sxl1 = xl[db + 64 + lane];
    edge_upd1(sxl0, sxl1, lav, xr0, xr1, a0, a1, sWe, lane, mr0, mr1, s0, s1, acc0, acc1);

    float h0 = acc0 / (s0 + 1e-16f) + bias[lane];
    float h1 = acc1 / (s1 + 1e-16f) + bias[64 + lane];
    hb[db + lane]      = h0 > 0.f ? h0 : expm1f(h0);
    hb[db + 64 + lane] = h1 > 0.f ? h1 : expm1f(h1);
}

// ---------------- fused edge phase, layer 2 (1 head x 64) ----------------

__device__ __forceinline__ void edge_upd2(float xlv, float av, float xrv, float a,
                                          const float* sWe, int lane,
                                          float& mr, float& s, float& acc) {
    float t = 0.f, u = 0.f;
#pragma unroll
    for (int d = 0; d < 16; ++d)
        t = fmaf(__shfl(av, d), sWe[d * OUTC + lane], t);
#pragma unroll
    for (int d = 16; d < 32; ++d)
        u = fmaf(__shfl(av, d), sWe[d * OUTC + lane], u);
    float m = (xlv + xrv) + (t + u);
    m = m > 0.f ? m : 0.2f * m;
    float p = m * a;
#pragma unroll
    for (int off = 32; off; off >>= 1) p += __shfl_xor(p, off);
    float nm = fmaxf(mr, p);
    float sc = __expf(mr - nm), e = __expf(p - nm);
    s = s * sc + e; acc = fmaf(acc, sc, e * xlv); mr = nm;
}

__global__ void __launch_bounds__(256) k_l2(
    const int2* __restrict__ esort, const int* __restrict__ offs,
    const float* __restrict__ ea, const float* __restrict__ We,
    const float* __restrict__ att, const float* __restrict__ xl,
    const float* __restrict__ xr, const float* __restrict__ bias,
    float* __restrict__ out) {
    __shared__ float sWe[EDIM * OUTC];  // 8 KB
    for (int i = threadIdx.x; i < EDIM * OUTC; i += 256) sWe[i] = We[i];
    __syncthreads();
    int lane = threadIdx.x & 63;
    int dst = (blockIdx.x << 2) + (threadIdx.x >> 6);
    if (dst >= NN) return;
    int beg = offs[dst], end = offs[dst + 1];
    int n = end - beg;
    float a = att[lane];
    size_t db = (size_t)dst * OUTC;
    float xrv = xr[db + lane];
    float mr = -INFINITY, s = 0.f, acc = 0.f, easum = 0.f;

    if (n > 0) {
        const int2* ep = esort + beg;
        int lastc = n - 1;
        int2 edA = ep[0];
        int2 edB = ep[min(1, lastc)];
        int2 edC = ep[min(2, lastc)];
        int2 edD = ep[min(3, lastc)];
        float Axl = xl[(size_t)edA.x * OUTC + lane];
        float Aav = ea[(size_t)edA.y * EDIM + (lane & 31)];
        float Bxl = xl[(size_t)edB.x * OUTC + lane];
        float Bav = ea[(size_t)edB.y * EDIM + (lane & 31)];
        int j = 0;
        while (j + 2 <= n) {
            float Cxl = xl[(size_t)edC.x * OUTC + lane];
            float Cav = ea[(size_t)edC.y * EDIM + (lane & 31)];
            int2 edE = ep[min(j + 4, lastc)];
            easum += Aav;
            edge_upd2(Axl, Aav, xrv, a, sWe, lane, mr, s, acc);
            float Dxl = xl[(size_t)edD.x * OUTC + lane];
            float Dav = ea[(size_t)edD.y * EDIM + (lane & 31)];
            int2 edF = ep[min(j + 5, lastc)];
            easum += Bav;
            edge_upd2(Bxl, Bav, xrv, a, sWe, lane, mr, s, acc);
            Axl = Cxl; Aav = Cav; Bxl = Dxl; Bav = Dav;
            edC = edE; edD = edF;
            j += 2;
        }
        if (j < n) {
            easum += Aav;
            edge_upd2(Axl, Aav, xrv, a, sWe, lane, mr, s, acc);
        }
    }

    float lav = easum * ((n > 0) ? (1.f / (float)n) : 1.f);
    float sxl = xl[db + lane];
    edge_upd2(sxl, lav, xrv, a, sWe, lane, mr, s, acc);

    out[db + lane] = acc / (s + 1e-16f) + bias[lane];
}

// ---------------- launch ----------------

extern "C" void kernel_launch(void* const* d_in, const int* in_sizes, int n_in,
                              void* d_out, int out_size, void* d_ws, size_t ws_size,
                              hipStream_t stream) {
    const float* x    = (const float*)d_in[0];
    const int*   ei   = (const int*)d_in[1];
    const float* ea   = (const float*)d_in[2];
    const float* Wl1  = (const float*)d_in[3];
    const float* bl1  = (const float*)d_in[4];
    const float* Wr1  = (const float*)d_in[5];
    const float* br1  = (const float*)d_in[6];
    const float* We1  = (const float*)d_in[7];
    const float* att1 = (const float*)d_in[8];
    const float* bias1= (const float*)d_in[9];
    const float* Wl2  = (const float*)d_in[10];
    const float* bl2  = (const float*)d_in[11];
    const float* Wr2  = (const float*)d_in[12];
    const float* br2  = (const float*)d_in[13];
    const float* We2  = (const float*)d_in[14];
    const float* att2 = (const float*)d_in[15];
    const float* bias2= (const float*)d_in[16];
    float* out = (float*)d_out;

    char* w = (char*)d_ws;
    int2* esort = (int2*)w;                 w += (size_t)EE * 8;        // 6.4 MB
    int*  offs  = (int*)w;                  w += (size_t)(NN + 4) * 4;
    int*  bsum  = (int*)w;                  w += 256 * 4;
    int*  bexcl = (int*)w;                  w += 256 * 4;
    int*  deg   = (int*)w;                  w += (size_t)NN * 4;
    float* xl1  = (float*)w;                w += (size_t)NN * H1C * 4;
    float* xr1  = (float*)w;                w += (size_t)NN * H1C * 4;
    float* hb   = (float*)w;                w += (size_t)NN * H1C * 4;
    float* xl2  = (float*)w;                w += (size_t)NN * OUTC * 4;
    float* xr2  = (float*)w;                w += (size_t)NN * OUTC * 4;

    hipMemsetAsync(deg, 0, (size_t)NN * 4, stream);

    // CSR build (edges sorted by dst)
    k_hist<<<(EE + 255) / 256, 256, 0, stream>>>(ei, deg);
    k_scan_block<<<NBLK, 256, 0, stream>>>(deg, offs, bsum);
    k_scan_top<<<1, 256, 0, stream>>>(bsum, bexcl);
    k_scan_add<<<NBLK, 256, 0, stream>>>(offs, bexcl);
    k_scatter<<<(EE + 255) / 256, 256, 0, stream>>>(ei, offs, deg, esort);

    // layer 1
    k_lin_pair<128><<<(NN + 31) / 32, 256, 0, stream>>>(x, Wl1, bl1, Wr1, br1, xl1, xr1);
    k_l1<<<(NN + 3) / 4, 256, 0, stream>>>(esort, offs, ea, We1, att1, xl1, xr1, bias1, hb);

    // layer 2
    k_lin_pair<64><<<(NN + 31) / 32, 128, 0, stream>>>(hb, Wl2, bl2, Wr2, br2, xl2, xr2);
    k_l2<<<(NN + 3) / 4, 256, 0, stream>>>(esort, offs, ea, We2, att2, xl2, xr2, bias2, out);
}

// Round 10
// 857.035 us; speedup vs baseline: 1.6291x; 1.5165x over previous
//
#include <hip/hip_runtime.h>
#include <cmath>

#define NN 50000
#define EE 800000
#define H1C 128        // heads*hid layer1
#define OUTC 64
#define EDIM 32
#define NBLK 196       // ceil(NN/256)

__device__ __forceinline__ float bcast(float v, int d) {
    return __int_as_float(__builtin_amdgcn_readlane(__float_as_int(v), d));
}

// ---------------- CSR build ----------------

__global__ void k_hist(const int* __restrict__ ei, int* deg) {
    int e = blockIdx.x * 256 + threadIdx.x;
    if (e < EE) atomicAdd(&deg[ei[EE + e]], 1);
}

__global__ void k_scan_block(const int* __restrict__ deg, int* offs, int* bsum) {
    __shared__ int s[256];
    int t = threadIdx.x;
    int gid = blockIdx.x * 256 + t;
    int v = (gid < NN) ? deg[gid] : 0;
    s[t] = v;
    __syncthreads();
    for (int off = 1; off < 256; off <<= 1) {
        int add = (t >= off) ? s[t - off] : 0;
        __syncthreads();
        s[t] += add;
        __syncthreads();
    }
    if (gid < NN) offs[gid] = s[t] - v;          // exclusive within block
    if (t == 255) bsum[blockIdx.x] = s[255];
}

__global__ void k_scan_top(const int* __restrict__ bsum, int* bexcl) {
    __shared__ int s[256];
    int t = threadIdx.x;
    int v = (t < NBLK) ? bsum[t] : 0;
    s[t] = v;
    __syncthreads();
    for (int off = 1; off < 256; off <<= 1) {
        int add = (t >= off) ? s[t - off] : 0;
        __syncthreads();
        s[t] += add;
        __syncthreads();
    }
    bexcl[t] = s[t] - v;
}

__global__ void k_scan_add(int* offs, const int* __restrict__ bexcl) {
    int gid = blockIdx.x * 256 + threadIdx.x;
    if (gid < NN) offs[gid] += bexcl[blockIdx.x];
    if (gid == 0) offs[NN] = EE;
}

__global__ void k_scatter(const int* __restrict__ ei, const int* __restrict__ offs,
                          int* deg, int2* esort) {
    int e = blockIdx.x * 256 + threadIdx.x;
    if (e >= EE) return;
    int dst = ei[EE + e];
    int idx = atomicSub(&deg[dst], 1) - 1;
    esort[offs[dst] + idx] = make_int2(ei[e], e);
}

// ---------------- fused pair of linears: oa = x@Wa+ba, ob = x@Wb+bb ----------------
// IL: store channel pairs (c, c+64) interleaved for single-dwordx2 edge gathers

template <int MO, bool IL>
__global__ void k_lin_pair(const float* __restrict__ x,
                           const float* __restrict__ Wa, const float* __restrict__ ba,
                           const float* __restrict__ Wb, const float* __restrict__ bb,
                           float* __restrict__ oa, float* __restrict__ ob) {
    __shared__ float xsT[128][36];   // transposed tile, padded
    int n0 = blockIdx.x * 32;
    int nthr = 2 * MO;
    for (int idx = threadIdx.x; idx < 32 * 128; idx += nthr) {
        int n = idx >> 7, k = idx & 127;
        xsT[k][n] = (n0 + n < NN) ? x[(size_t)(n0 + n) * 128 + k] : 0.f;
    }
    __syncthreads();
    int t = threadIdx.x;
    const float* W  = (t < MO) ? Wa : Wb;
    const float* bp = (t < MO) ? ba : bb;
    float* op       = (t < MO) ? oa : ob;
    int m = (t < MO) ? t : t - MO;
    float bv = bp[m];
    float acc[32];
#pragma unroll
    for (int n = 0; n < 32; ++n) acc[n] = bv;
#pragma unroll 2
    for (int k = 0; k < 128; ++k) {
        float w = W[k * MO + m];
        const float4* row = reinterpret_cast<const float4*>(&xsT[k][0]);
#pragma unroll
        for (int c = 0; c < 8; ++c) {
            float4 v = row[c];
            acc[4 * c + 0] = fmaf(v.x, w, acc[4 * c + 0]);
            acc[4 * c + 1] = fmaf(v.y, w, acc[4 * c + 1]);
            acc[4 * c + 2] = fmaf(v.z, w, acc[4 * c + 2]);
            acc[4 * c + 3] = fmaf(v.w, w, acc[4 * c + 3]);
        }
    }
    int mo = IL ? (((m & 63) << 1) + (m >> 6)) : m;
#pragma unroll
    for (int n = 0; n < 32; ++n)
        if (n0 + n < NN) op[(size_t)(n0 + n) * MO + mo] = acc[n];
}

// ---------------- fused edge phase, layer 1 (2 heads x 64) ----------------
// We held in VGPRs (wr0/wr1); no LDS at all.

__device__ __forceinline__ void edge_upd1(float2 xlv, float av,
                                          float2 xrv, float a0, float a1,
                                          const float (&wr0)[32], const float (&wr1)[32],
                                          float& mr0, float& mr1, float& s0, float& s1,
                                          float& acc0, float& acc1) {
    float t0 = 0.f, t1 = 0.f, u0 = 0.f, u1 = 0.f;
#pragma unroll
    for (int d = 0; d < 16; ++d) {
        float a = bcast(av, d);
        t0 = fmaf(a, wr0[d], t0);
        t1 = fmaf(a, wr1[d], t1);
    }
#pragma unroll
    for (int d = 16; d < 32; ++d) {
        float a = bcast(av, d);
        u0 = fmaf(a, wr0[d], u0);
        u1 = fmaf(a, wr1[d], u1);
    }
    float m0 = (xlv.x + xrv.x) + (t0 + u0);
    float m1 = (xlv.y + xrv.y) + (t1 + u1);
    m0 = m0 > 0.f ? m0 : 0.2f * m0;
    m1 = m1 > 0.f ? m1 : 0.2f * m1;
    float p0 = m0 * a0, p1 = m1 * a1;
#pragma unroll
    for (int off = 32; off; off >>= 1) { p0 += __shfl_xor(p0, off); p1 += __shfl_xor(p1, off); }
    float nm = fmaxf(mr0, p0);
    float sc = __expf(mr0 - nm), e = __expf(p0 - nm);
    s0 = s0 * sc + e; acc0 = fmaf(acc0, sc, e * xlv.x); mr0 = nm;
    nm = fmaxf(mr1, p1);
    sc = __expf(mr1 - nm); e = __expf(p1 - nm);
    s1 = s1 * sc + e; acc1 = fmaf(acc1, sc, e * xlv.y); mr1 = nm;
}

__global__ void __launch_bounds__(256) k_l1(
    const int2* __restrict__ esort, const int* __restrict__ offs,
    const float* __restrict__ ea, const float* __restrict__ We,
    const float* __restrict__ att, const float* __restrict__ xl,
    const float* __restrict__ xr, const float* __restrict__ bias,
    float* __restrict__ hb) {
    int lane = threadIdx.x & 63;
    float wr0[32], wr1[32];
#pragma unroll
    for (int d = 0; d < 32; ++d) {
        wr0[d] = We[d * H1C + lane];
        wr1[d] = We[d * H1C + 64 + lane];
    }
    int dst = (blockIdx.x << 2) + (threadIdx.x >> 6);
    if (dst >= NN) return;
    int beg = offs[dst], end = offs[dst + 1];
    int n = end - beg;
    float a0 = att[lane], a1 = att[64 + lane];
    size_t db = (size_t)dst * H1C;
    float2 xrv = reinterpret_cast<const float2*>(xr + db)[lane];
    float mr0 = -INFINITY, mr1 = -INFINITY;
    float s0 = 0.f, s1 = 0.f, acc0 = 0.f, acc1 = 0.f, easum = 0.f;

    float2 xlv = make_float2(0.f, 0.f);
    float av = 0.f;
    if (n > 0) {                        // preload first edge
        int2 ed = esort[beg];
        xlv = reinterpret_cast<const float2*>(xl + (size_t)ed.x * H1C)[lane];
        av = ea[(size_t)ed.y * EDIM + (lane & 31)];
    }
    for (int j = beg; j < end; ++j) {
        float2 cxl = xlv; float cav = av;
        if (j + 1 < end) {              // issue next edge's loads before compute
            int2 ed = esort[j + 1];
            xlv = reinterpret_cast<const float2*>(xl + (size_t)ed.x * H1C)[lane];
            av = ea[(size_t)ed.y * EDIM + (lane & 31)];
        }
        easum += cav;
        edge_upd1(cxl, cav, xrv, a0, a1, wr0, wr1, mr0, mr1, s0, s1, acc0, acc1);
    }

    // self loop: attr = mean of incoming edge attrs (0 if no edges)
    float lav = easum * ((n > 0) ? (1.f / (float)n) : 1.f);
    float2 sxl = reinterpret_cast<const float2*>(xl + db)[lane];
    edge_upd1(sxl, lav, xrv, a0, a1, wr0, wr1, mr0, mr1, s0, s1, acc0, acc1);

    float h0 = acc0 / (s0 + 1e-16f) + bias[lane];
    float h1 = acc1 / (s1 + 1e-16f) + bias[64 + lane];
    hb[db + lane]      = h0 > 0.f ? h0 : expm1f(h0);
    hb[db + 64 + lane] = h1 > 0.f ? h1 : expm1f(h1);
}

// ---------------- fused edge phase, layer 2 (1 head x 64) ----------------

__device__ __forceinline__ void edge_upd2(float xlv, float av, float xrv, float a,
                                          const float (&wr)[32],
                                          float& mr, float& s, float& acc) {
    float t = 0.f, u = 0.f;
#pragma unroll
    for (int d = 0; d < 16; ++d)
        t = fmaf(bcast(av, d), wr[d], t);
#pragma unroll
    for (int d = 16; d < 32; ++d)
        u = fmaf(bcast(av, d), wr[d], u);
    float m = (xlv + xrv) + (t + u);
    m = m > 0.f ? m : 0.2f * m;
    float p = m * a;
#pragma unroll
    for (int off = 32; off; off >>= 1) p += __shfl_xor(p, off);
    float nm = fmaxf(mr, p);
    float sc = __expf(mr - nm), e = __expf(p - nm);
    s = s * sc + e; acc = fmaf(acc, sc, e * xlv); mr = nm;
}

__global__ void __launch_bounds__(256) k_l2(
    const int2* __restrict__ esort, const int* __restrict__ offs,
    const float* __restrict__ ea, const float* __restrict__ We,
    const float* __restrict__ att, const float* __restrict__ xl,
    const float* __restrict__ xr, const float* __restrict__ bias,
    float* __restrict__ out) {
    int lane = threadIdx.x & 63;
    float wr[32];
#pragma unroll
    for (int d = 0; d < 32; ++d) wr[d] = We[d * OUTC + lane];
    int dst = (blockIdx.x << 2) + (threadIdx.x >> 6);
    if (dst >= NN) return;
    int beg = offs[dst], end = offs[dst + 1];
    int n = end - beg;
    float a = att[lane];
    size_t db = (size_t)dst * OUTC;
    float xrv = xr[db + lane];
    float mr = -INFINITY, s = 0.f, acc = 0.f, easum = 0.f;

    float xlv = 0.f, av = 0.f;
    if (n > 0) {
        int2 ed = esort[beg];
        xlv = xl[(size_t)ed.x * OUTC + lane];
        av = ea[(size_t)ed.y * EDIM + (lane & 31)];
    }
    for (int j = beg; j < end; ++j) {
        float cxl = xlv, cav = av;
        if (j + 1 < end) {
            int2 ed = esort[j + 1];
            xlv = xl[(size_t)ed.x * OUTC + lane];
            av = ea[(size_t)ed.y * EDIM + (lane & 31)];
        }
        easum += cav;
        edge_upd2(cxl, cav, xrv, a, wr, mr, s, acc);
    }
    float lav = easum * ((n > 0) ? (1.f / (float)n) : 1.f);
    float sxl = xl[db + lane];
    edge_upd2(sxl, lav, xrv, a, wr, mr, s, acc);

    out[db + lane] = acc / (s + 1e-16f) + bias[lane];
}

// ---------------- launch ----------------

extern "C" void kernel_launch(void* const* d_in, const int* in_sizes, int n_in,
                              void* d_out, int out_size, void* d_ws, size_t ws_size,
                              hipStream_t stream) {
    const float* x    = (const float*)d_in[0];
    const int*   ei   = (const int*)d_in[1];
    const float* ea   = (const float*)d_in[2];
    const float* Wl1  = (const float*)d_in[3];
    const float* bl1  = (const float*)d_in[4];
    const float* Wr1  = (const float*)d_in[5];
    const float* br1  = (const float*)d_in[6];
    const float* We1  = (const float*)d_in[7];
    const float* att1 = (const float*)d_in[8];
    const float* bias1= (const float*)d_in[9];
    const float* Wl2  = (const float*)d_in[10];
    const float* bl2  = (const float*)d_in[11];
    const float* Wr2  = (const float*)d_in[12];
    const float* br2  = (const float*)d_in[13];
    const float* We2  = (const float*)d_in[14];
    const float* att2 = (const float*)d_in[15];
    const float* bias2= (const float*)d_in[16];
    float* out = (float*)d_out;

    char* w = (char*)d_ws;
    int2* esort = (int2*)w;                 w += (size_t)EE * 8;        // 6.4 MB
    int*  offs  = (int*)w;                  w += (size_t)(NN + 4) * 4;
    int*  bsum  = (int*)w;                  w += 256 * 4;
    int*  bexcl = (int*)w;                  w += 256 * 4;
    int*  deg   = (int*)w;                  w += (size_t)NN * 4;
    float* xl1  = (float*)w;                w += (size_t)NN * H1C * 4;  // interleaved (c,c+64)
    float* xr1  = (float*)w;                w += (size_t)NN * H1C * 4;  // interleaved
    float* hb   = (float*)w;                w += (size_t)NN * H1C * 4;  // normal layout
    float* xl2  = (float*)w;                w += (size_t)NN * OUTC * 4;
    float* xr2  = (float*)w;                w += (size_t)NN * OUTC * 4;

    hipMemsetAsync(deg, 0, (size_t)NN * 4, stream);

    // CSR build (edges sorted by dst)
    k_hist<<<(EE + 255) / 256, 256, 0, stream>>>(ei, deg);
    k_scan_block<<<NBLK, 256, 0, stream>>>(deg, offs, bsum);
    k_scan_top<<<1, 256, 0, stream>>>(bsum, bexcl);
    k_scan_add<<<NBLK, 256, 0, stream>>>(offs, bexcl);
    k_scatter<<<(EE + 255) / 256, 256, 0, stream>>>(ei, offs, deg, esort);

    // layer 1
    k_lin_pair<128, true><<<(NN + 31) / 32, 256, 0, stream>>>(x, Wl1, bl1, Wr1, br1, xl1, xr1);
    k_l1<<<(NN + 3) / 4, 256, 0, stream>>>(esort, offs, ea, We1, att1, xl1, xr1, bias1, hb);

    // layer 2
    k_lin_pair<64, false><<<(NN + 31) / 32, 128, 0, stream>>>(hb, Wl2, bl2, Wr2, br2, xl2, xr2);
    k_l2<<<(NN + 3) / 4, 256, 0, stream>>>(esort, offs, ea, We2, att2, xl2, xr2, bias2, out);
}

// Round 13
// 809.701 us; speedup vs baseline: 1.7243x; 1.0585x over previous
//
#include <hip/hip_runtime.h>
#include <cmath>

#define NN 50000
#define EE 800000
#define H1C 128        // heads*hid layer1
#define OUTC 64
#define EDIM 32
#define NBLK 196       // ceil(NN/256)

__device__ __forceinline__ float bcast(float v, int d) {
    return __int_as_float(__builtin_amdgcn_readlane(__float_as_int(v), d));
}

// wave64 sum via DPP (LLVM AtomicOptimizer sequence); result broadcast from lane 63
template <int CTRL, int RM>
__device__ __forceinline__ float dpp_add(float x) {
    int y = __builtin_amdgcn_update_dpp(0, __float_as_int(x), CTRL, RM, 0xf, false);
    return x + __int_as_float(y);
}
__device__ __forceinline__ float wsum64(float x) {
    x = dpp_add<0x111, 0xf>(x);   // row_shr:1
    x = dpp_add<0x112, 0xf>(x);   // row_shr:2
    x = dpp_add<0x114, 0xf>(x);   // row_shr:4
    x = dpp_add<0x118, 0xf>(x);   // row_shr:8
    x = dpp_add<0x142, 0xa>(x);   // row_bcast:15 -> rows 1,3
    x = dpp_add<0x143, 0xc>(x);   // row_bcast:31 -> rows 2,3
    return __int_as_float(__builtin_amdgcn_readlane(__float_as_int(x), 63));
}

// ---------------- CSR build ----------------

__global__ void k_hist(const int* __restrict__ ei, int* deg) {
    int e = blockIdx.x * 256 + threadIdx.x;
    if (e < EE) atomicAdd(&deg[ei[EE + e]], 1);
}

__global__ void k_scan_block(const int* __restrict__ deg, int* offs, int* bsum) {
    __shared__ int s[256];
    int t = threadIdx.x;
    int gid = blockIdx.x * 256 + t;
    int v = (gid < NN) ? deg[gid] : 0;
    s[t] = v;
    __syncthreads();
    for (int off = 1; off < 256; off <<= 1) {
        int add = (t >= off) ? s[t - off] : 0;
        __syncthreads();
        s[t] += add;
        __syncthreads();
    }
    if (gid < NN) offs[gid] = s[t] - v;          // exclusive within block
    if (t == 255) bsum[blockIdx.x] = s[255];
}

__global__ void k_scan_top(const int* __restrict__ bsum, int* bexcl) {
    __shared__ int s[256];
    int t = threadIdx.x;
    int v = (t < NBLK) ? bsum[t] : 0;
    s[t] = v;
    __syncthreads();
    for (int off = 1; off < 256; off <<= 1) {
        int add = (t >= off) ? s[t - off] : 0;
        __syncthreads();
        s[t] += add;
        __syncthreads();
    }
    bexcl[t] = s[t] - v;
}

__global__ void k_scan_add(int* offs, const int* __restrict__ bexcl) {
    int gid = blockIdx.x * 256 + threadIdx.x;
    if (gid < NN) offs[gid] += bexcl[blockIdx.x];
    if (gid == 0) offs[NN] = EE;
}

__global__ void k_scatter(const int* __restrict__ ei, const int* __restrict__ offs,
                          int* deg, int2* esort) {
    int e = blockIdx.x * 256 + threadIdx.x;
    if (e >= EE) return;
    int dst = ei[EE + e];
    int idx = atomicSub(&deg[dst], 1) - 1;
    esort[offs[dst] + idx] = make_int2(ei[e], e);
}

// ---------------- fused pair of linears: oa = x@Wa+ba, ob = x@Wb+bb ----------------
// IL: store channel pairs (c, c+64) interleaved for single-dwordx2 edge gathers

template <int MO, bool IL>
__global__ void k_lin_pair(const float* __restrict__ x,
                           const float* __restrict__ Wa, const float* __restrict__ ba,
                           const float* __restrict__ Wb, const float* __restrict__ bb,
                           float* __restrict__ oa, float* __restrict__ ob) {
    __shared__ float xsT[128][36];   // transposed tile, padded
    int n0 = blockIdx.x * 32;
    int nthr = 2 * MO;
    for (int idx = threadIdx.x; idx < 32 * 128; idx += nthr) {
        int n = idx >> 7, k = idx & 127;
        xsT[k][n] = (n0 + n < NN) ? x[(size_t)(n0 + n) * 128 + k] : 0.f;
    }
    __syncthreads();
    int t = threadIdx.x;
    const float* W  = (t < MO) ? Wa : Wb;
    const float* bp = (t < MO) ? ba : bb;
    float* op       = (t < MO) ? oa : ob;
    int m = (t < MO) ? t : t - MO;
    float bv = bp[m];
    float acc[32];
#pragma unroll
    for (int n = 0; n < 32; ++n) acc[n] = bv;
#pragma unroll 2
    for (int k = 0; k < 128; ++k) {
        float w = W[k * MO + m];
        const float4* row = reinterpret_cast<const float4*>(&xsT[k][0]);
#pragma unroll
        for (int c = 0; c < 8; ++c) {
            float4 v = row[c];
            acc[4 * c + 0] = fmaf(v.x, w, acc[4 * c + 0]);
            acc[4 * c + 1] = fmaf(v.y, w, acc[4 * c + 1]);
            acc[4 * c + 2] = fmaf(v.z, w, acc[4 * c + 2]);
            acc[4 * c + 3] = fmaf(v.w, w, acc[4 * c + 3]);
        }
    }
    int mo = IL ? (((m & 63) << 1) + (m >> 6)) : m;
#pragma unroll
    for (int n = 0; n < 32; ++n)
        if (n0 + n < NN) op[(size_t)(n0 + n) * MO + mo] = acc[n];
}

// ---------------- fused edge phase, layer 1 (2 heads x 64) ----------------

__device__ __forceinline__ void dot1(float av, const float (&wr0)[32], const float (&wr1)[32],
                                     float& q0, float& q1) {
    float t0 = 0.f, t1 = 0.f, u0 = 0.f, u1 = 0.f;
#pragma unroll
    for (int d = 0; d < 16; ++d) {
        float a = bcast(av, d);
        t0 = fmaf(a, wr0[d], t0);
        t1 = fmaf(a, wr1[d], t1);
    }
#pragma unroll
    for (int d = 16; d < 32; ++d) {
        float a = bcast(av, d);
        u0 = fmaf(a, wr0[d], u0);
        u1 = fmaf(a, wr1[d], u1);
    }
    q0 = t0 + u0; q1 = t1 + u1;
}

__device__ __forceinline__ void fin1(float2 xlv, float q0, float q1, float2 xrv,
                                     float a0, float a1,
                                     float& mr0, float& mr1, float& s0, float& s1,
                                     float& acc0, float& acc1) {
    float m0 = (xlv.x + xrv.x) + q0;
    float m1 = (xlv.y + xrv.y) + q1;
    m0 = m0 > 0.f ? m0 : 0.2f * m0;
    m1 = m1 > 0.f ? m1 : 0.2f * m1;
    float p0 = wsum64(m0 * a0);
    float p1 = wsum64(m1 * a1);
    float nm = fmaxf(mr0, p0);
    float sc = __expf(mr0 - nm), e = __expf(p0 - nm);
    s0 = s0 * sc + e; acc0 = fmaf(acc0, sc, e * xlv.x); mr0 = nm;
    nm = fmaxf(mr1, p1);
    sc = __expf(mr1 - nm); e = __expf(p1 - nm);
    s1 = s1 * sc + e; acc1 = fmaf(acc1, sc, e * xlv.y); mr1 = nm;
}

__global__ void __launch_bounds__(256, 4) k_l1(
    const int2* __restrict__ esort, const int* __restrict__ offs,
    const float* __restrict__ ea, const float* __restrict__ We,
    const float* __restrict__ att, const float* __restrict__ xl,
    const float* __restrict__ xr, const float* __restrict__ bias,
    float* __restrict__ hb) {
    int lane = threadIdx.x & 63;
    float wr0[32], wr1[32];               // We columns held in VGPRs (128-reg budget)
#pragma unroll
    for (int d = 0; d < 32; ++d) {
        wr0[d] = We[d * H1C + lane];
        wr1[d] = We[d * H1C + 64 + lane];
    }
    int dst = (blockIdx.x << 2) + (threadIdx.x >> 6);
    if (dst >= NN) return;
    int beg = offs[dst], end = offs[dst + 1];
    int n = end - beg;
    float a0 = att[lane], a1 = att[64 + lane];
    size_t db = (size_t)dst * H1C;
    float2 xrv = reinterpret_cast<const float2*>(xr + db)[lane];
    float mr0 = -INFINITY, mr1 = -INFINITY;
    float s0 = 0.f, s1 = 0.f, acc0 = 0.f, acc1 = 0.f, easum = 0.f;

    // depth-2 prefetch: slot A = edge j, slot B = edge j+1
    float2 xlA = make_float2(0.f, 0.f), xlB = make_float2(0.f, 0.f);
    float avA = 0.f, avB = 0.f;
    if (n > 0) {
        int2 ed = esort[beg];
        xlA = reinterpret_cast<const float2*>(xl + (size_t)ed.x * H1C)[lane];
        avA = ea[(size_t)ed.y * EDIM + (lane & 31)];
    }
    if (n > 1) {
        int2 ed = esort[beg + 1];
        xlB = reinterpret_cast<const float2*>(xl + (size_t)ed.x * H1C)[lane];
        avB = ea[(size_t)ed.y * EDIM + (lane & 31)];
    }
    int j = beg;
    for (; j + 2 <= end; j += 2) {
        float q0, q1;
        easum += avA;
        dot1(avA, wr0, wr1, q0, q1);     // consumes avA; regs free for reload
        float2 c = xlA;
        if (j + 2 < end) {               // wave-uniform guard
            int2 ed = esort[j + 2];
            xlA = reinterpret_cast<const float2*>(xl + (size_t)ed.x * H1C)[lane];
            avA = ea[(size_t)ed.y * EDIM + (lane & 31)];
        }
        fin1(c, q0, q1, xrv, a0, a1, mr0, mr1, s0, s1, acc0, acc1);
        easum += avB;
        dot1(avB, wr0, wr1, q0, q1);
        float2 d2 = xlB;
        if (j + 3 < end) {
            int2 ed = esort[j + 3];
            xlB = reinterpret_cast<const float2*>(xl + (size_t)ed.x * H1C)[lane];
            avB = ea[(size_t)ed.y * EDIM + (lane & 31)];
        }
        fin1(d2, q0, q1, xrv, a0, a1, mr0, mr1, s0, s1, acc0, acc1);
    }
    if (j < end) {
        float q0, q1;
        easum += avA;
        dot1(avA, wr0, wr1, q0, q1);
        fin1(xlA, q0, q1, xrv, a0, a1, mr0, mr1, s0, s1, acc0, acc1);
    }

    // self loop: attr = mean of incoming edge attrs (0 if no edges)
    float lav = easum * ((n > 0) ? (1.f / (float)n) : 1.f);
    float q0, q1;
    dot1(lav, wr0, wr1, q0, q1);
    float2 sxl = reinterpret_cast<const float2*>(xl + db)[lane];
    fin1(sxl, q0, q1, xrv, a0, a1, mr0, mr1, s0, s1, acc0, acc1);

    float h0 = acc0 / (s0 + 1e-16f) + bias[lane];
    float h1 = acc1 / (s1 + 1e-16f) + bias[64 + lane];
    hb[db + lane]      = h0 > 0.f ? h0 : expm1f(h0);
    hb[db + 64 + lane] = h1 > 0.f ? h1 : expm1f(h1);
}

// ---------------- fused edge phase, layer 2 (1 head x 64) ----------------

__device__ __forceinline__ float dot2(float av, const float (&wr)[32]) {
    float t = 0.f, u = 0.f;
#pragma unroll
    for (int d = 0; d < 16; ++d) t = fmaf(bcast(av, d), wr[d], t);
#pragma unroll
    for (int d = 16; d < 32; ++d) u = fmaf(bcast(av, d), wr[d], u);
    return t + u;
}

__device__ __forceinline__ void fin2(float xlv, float q, float xrv, float a,
                                     float& mr, float& s, float& acc) {
    float m = (xlv + xrv) + q;
    m = m > 0.f ? m : 0.2f * m;
    float p = wsum64(m * a);
    float nm = fmaxf(mr, p);
    float sc = __expf(mr - nm), e = __expf(p - nm);
    s = s * sc + e; acc = fmaf(acc, sc, e * xlv); mr = nm;
}

__global__ void __launch_bounds__(256, 4) k_l2(
    const int2* __restrict__ esort, const int* __restrict__ offs,
    const float* __restrict__ ea, const float* __restrict__ We,
    const float* __restrict__ att, const float* __restrict__ xl,
    const float* __restrict__ xr, const float* __restrict__ bias,
    float* __restrict__ out) {
    int lane = threadIdx.x & 63;
    float wr[32];
#pragma unroll
    for (int d = 0; d < 32; ++d) wr[d] = We[d * OUTC + lane];
    int dst = (blockIdx.x << 2) + (threadIdx.x >> 6);
    if (dst >= NN) return;
    int beg = offs[dst], end = offs[dst + 1];
    int n = end - beg;
    float a = att[lane];
    size_t db = (size_t)dst * OUTC;
    float xrv = xr[db + lane];
    float mr = -INFINITY, s = 0.f, acc = 0.f, easum = 0.f;

    float xlA = 0.f, xlB = 0.f, avA = 0.f, avB = 0.f;
    if (n > 0) {
        int2 ed = esort[beg];
        xlA = xl[(size_t)ed.x * OUTC + lane];
        avA = ea[(size_t)ed.y * EDIM + (lane & 31)];
    }
    if (n > 1) {
        int2 ed = esort[beg + 1];
        xlB = xl[(size_t)ed.x * OUTC + lane];
        avB = ea[(size_t)ed.y * EDIM + (lane & 31)];
    }
    int j = beg;
    for (; j + 2 <= end; j += 2) {
        easum += avA;
        float q = dot2(avA, wr);
        float c = xlA;
        if (j + 2 < end) {
            int2 ed = esort[j + 2];
            xlA = xl[(size_t)ed.x * OUTC + lane];
            avA = ea[(size_t)ed.y * EDIM + (lane & 31)];
        }
        fin2(c, q, xrv, a, mr, s, acc);
        easum += avB;
        q = dot2(avB, wr);
        float d2 = xlB;
        if (j + 3 < end) {
            int2 ed = esort[j + 3];
            xlB = xl[(size_t)ed.x * OUTC + lane];
            avB = ea[(size_t)ed.y * EDIM + (lane & 31)];
        }
        fin2(d2, q, xrv, a, mr, s, acc);
    }
    if (j < end) {
        easum += avA;
        float q = dot2(avA, wr);
        fin2(xlA, q, xrv, a, mr, s, acc);
    }

    float lav = easum * ((n > 0) ? (1.f / (float)n) : 1.f);
    float q = dot2(lav, wr);
    float sxl = xl[db + lane];
    fin2(sxl, q, xrv, a, mr, s, acc);

    out[db + lane] = acc / (s + 1e-16f) + bias[lane];
}

// ---------------- launch ----------------

extern "C" void kernel_launch(void* const* d_in, const int* in_sizes, int n_in,
                              void* d_out, int out_size, void* d_ws, size_t ws_size,
                              hipStream_t stream) {
    const float* x    = (const float*)d_in[0];
    const int*   ei   = (const int*)d_in[1];
    const float* ea   = (const float*)d_in[2];
    const float* Wl1  = (const float*)d_in[3];
    const float* bl1  = (const float*)d_in[4];
    const float* Wr1  = (const float*)d_in[5];
    const float* br1  = (const float*)d_in[6];
    const float* We1  = (const float*)d_in[7];
    const float* att1 = (const float*)d_in[8];
    const float* bias1= (const float*)d_in[9];
    const float* Wl2  = (const float*)d_in[10];
    const float* bl2  = (const float*)d_in[11];
    const float* Wr2  = (const float*)d_in[12];
    const float* br2  = (const float*)d_in[13];
    const float* We2  = (const float*)d_in[14];
    const float* att2 = (const float*)d_in[15];
    const float* bias2= (const float*)d_in[16];
    float* out = (float*)d_out;

    char* w = (char*)d_ws;
    int2* esort = (int2*)w;                 w += (size_t)EE * 8;        // 6.4 MB
    int*  offs  = (int*)w;                  w += (size_t)(NN + 4) * 4;
    int*  bsum  = (int*)w;                  w += 256 * 4;
    int*  bexcl = (int*)w;                  w += 256 * 4;
    int*  deg   = (int*)w;                  w += (size_t)NN * 4;
    float* xl1  = (float*)w;                w += (size_t)NN * H1C * 4;  // interleaved (c,c+64)
    float* xr1  = (float*)w;                w += (size_t)NN * H1C * 4;  // interleaved
    float* hb   = (float*)w;                w += (size_t)NN * H1C * 4;  // normal layout
    float* xl2  = (float*)w;                w += (size_t)NN * OUTC * 4;
    float* xr2  = (float*)w;                w += (size_t)NN * OUTC * 4;

    (void)hipMemsetAsync(deg, 0, (size_t)NN * 4, stream);

    // CSR build (edges sorted by dst)
    k_hist<<<(EE + 255) / 256, 256, 0, stream>>>(ei, deg);
    k_scan_block<<<NBLK, 256, 0, stream>>>(deg, offs, bsum);
    k_scan_top<<<1, 256, 0, stream>>>(bsum, bexcl);
    k_scan_add<<<NBLK, 256, 0, stream>>>(offs, bexcl);
    k_scatter<<<(EE + 255) / 256, 256, 0, stream>>>(ei, offs, deg, esort);

    // layer 1
    k_lin_pair<128, true><<<(NN + 31) / 32, 256, 0, stream>>>(x, Wl1, bl1, Wr1, br1, xl1, xr1);
    k_l1<<<(NN + 3) / 4, 256, 0, stream>>>(esort, offs, ea, We1, att1, xl1, xr1, bias1, hb);

    // layer 2
    k_lin_pair<64, false><<<(NN + 31) / 32, 128, 0, stream>>>(hb, Wl2, bl2, Wr2, br2, xl2, xr2);
    k_l2<<<(NN + 3) / 4, 256, 0, stream>>>(esort, offs, ea, We2, att2, xl2, xr2, bias2, out);
}